// Round 12
// baseline (51.735 us; speedup 1.0000x reference)
//
#include <hip/hip_runtime.h>
#include <math.h>
#include <stdint.h>

#define NN 8192
#define DD 1024
#define KT 2048   // 2*D
#define HH 100
#define HP 128    // padded hidden
#define LCAP 512
#define NB 32
#define NCH 16    // 64-k sub-bodies per K-half

typedef short bf16x8 __attribute__((ext_vector_type(8)));
typedef short bf16x4 __attribute__((ext_vector_type(4)));
typedef float f32x4 __attribute__((ext_vector_type(4)));

__device__ __forceinline__ short f2bf(float f) {
    uint32_t u = __builtin_bit_cast(uint32_t, f);
    u += 0x7FFF + ((u >> 16) & 1);   // round-to-nearest-even
    return (short)(u >> 16);
}

// W1 fp32 [2048][100] -> w1p packed fragments (coalesced B loads).
// Block 0 also zeroes the compaction counters.
__global__ __launch_bounds__(256) void prep_w1p(const float* __restrict__ W1,
                                                short* __restrict__ w1p,
                                                int* __restrict__ cnt1,
                                                int* __restrict__ cnt0)
{
    __shared__ float ld[32][104];
    const int t  = threadIdx.x;
    if (blockIdx.x == 0 && t < 64) {
        if (t < 32) cnt1[t] = 0; else cnt0[t - 32] = 0;
    }
    const int k0 = blockIdx.x * 32;          // 64 blocks
    for (int i = t; i < 32 * HH; i += 256) {
        const int kk = i / HH, cc = i - kk * HH;
        ld[kk][cc] = W1[(size_t)(k0 + kk) * HH + cc];
    }
    __syncthreads();
    for (int idx = t; idx < 512; idx += 256) {
        const int tt = idx >> 6, l = idx & 63;
        const int lr = l & 15, lg = l >> 4;
        const int col = tt * 16 + lr;
        bf16x8 r;
#pragma unroll
        for (int j = 0; j < 8; ++j)
            r[j] = (col < HH) ? f2bf(ld[lg * 8 + j][col]) : (short)0;
        *(bf16x8*)(w1p + ((size_t)(blockIdx.x * 8 + tt) * 64 + l) * 8) = r;
    }
}

// 512 thr / 8 waves; 16 rows/block. Waves 0-3: K half 0 (q); waves 4-7: half 1 (x).
// Whole K-half A staged to LDS ONCE (1 barrier), then a barrier-free K-loop:
// 16 sub-bodies of {coalesced packed-B loads (reg dbuf), 4 ds_read, 4 MFMA}.
__global__ __launch_bounds__(512) void encoder_mfma(
    const float* __restrict__ q, const float* __restrict__ x,
    const short* __restrict__ w1p,
    const float* __restrict__ b1, const float* __restrict__ W2,
    const float* __restrict__ b2,
    const int* __restrict__ bidx, const int* __restrict__ y,
    float* __restrict__ sp, float* __restrict__ sn,
    int* __restrict__ cnt1, int* __restrict__ cnt0)
{
    __shared__ short As[2][16][NCH][64];  // 64 KB: [half][row][chunk][64k], swizzled 8B slots
    __shared__ float hsum[16][HP + 4];
    __shared__ float fold[4][16];
    const int t    = threadIdx.x;
    const int w    = t >> 6;             // 0..7
    const int half = w >> 2;             // K half
    const int wc   = w & 3;              // col wave
    const int l    = t & 63;
    const int lr   = l & 15;
    const int lg   = l >> 4;
    const int r0   = blockIdx.x * 16;

    // ---- stage entire K-half: 16 coalesced float4 loads/thread, 2 batches ----
    const int ts    = t & 255;
    const int srow  = ts >> 4;
    const int sslot = ts & 15;
    const int wslot = (sslot ^ srow) * 4;
    const float* abase = (half ? x : q) + (size_t)(r0 + srow) * DD + sslot * 4;
    auto cvt4 = [&](const float4& v) {
        bf16x4 s;
        s[0] = f2bf(v.x); s[1] = f2bf(v.y); s[2] = f2bf(v.z); s[3] = f2bf(v.w);
        return s;
    };
    {
        float4 g[8];
#pragma unroll
        for (int p = 0; p < 8; ++p) g[p] = *(const float4*)(abase + p * 64);
#pragma unroll
        for (int p = 0; p < 8; ++p)
            *(bf16x4*)&As[half][srow][p][wslot] = cvt4(g[p]);
#pragma unroll
        for (int p = 0; p < 8; ++p) g[p] = *(const float4*)(abase + (p + 8) * 64);
#pragma unroll
        for (int p = 0; p < 8; ++p)
            *(bf16x4*)&As[half][srow][p + 8][wslot] = cvt4(g[p]);
    }
    __syncthreads();   // the ONLY barrier before the epilogue

    // ---- barrier-free K-loop ----
    const int p0 = ((2 * lg)     ^ lr) * 4;
    const int p1 = ((2 * lg + 1) ^ lr) * 4;
    const int p2 = ((2 * lg + 8) ^ lr) * 4;
    const int p3 = ((2 * lg + 9) ^ lr) * 4;

    const short* pB = w1p + (size_t)half * NCH * 8192
                    + ((size_t)(2 * wc) * 64 + l) * 8;
#define LOADB(c, x0, x1, x2, x3)                           \
    { const size_t e_ = (size_t)(c) * 8192;                \
      x0 = *(const bf16x8*)(pB + e_);                      \
      x1 = *(const bf16x8*)(pB + e_ + 4096);               \
      x2 = *(const bf16x8*)(pB + e_ + 512);                \
      x3 = *(const bf16x8*)(pB + e_ + 4096 + 512); }

    f32x4 acc0 = (f32x4)0.f, acc1 = (f32x4)0.f;
    bf16x8 bA0, bA1, bA2, bA3, bB0, bB1, bB2, bB3;

#define FRAGS_MFMA(c, b0, b1_, b2_, b3_)                                    \
    { const short* ar = &As[half][lr][c][0];                                \
      bf16x4 g0 = *(const bf16x4*)(ar + p0);                                \
      bf16x4 g1 = *(const bf16x4*)(ar + p1);                                \
      bf16x4 g2 = *(const bf16x4*)(ar + p2);                                \
      bf16x4 g3 = *(const bf16x4*)(ar + p3);                                \
      bf16x8 aa0 = __builtin_shufflevector(g0, g1, 0,1,2,3,4,5,6,7);        \
      bf16x8 aa1 = __builtin_shufflevector(g2, g3, 0,1,2,3,4,5,6,7);        \
      acc0 = __builtin_amdgcn_mfma_f32_16x16x32_bf16(aa0, b0,  acc0, 0,0,0);\
      acc0 = __builtin_amdgcn_mfma_f32_16x16x32_bf16(aa1, b1_, acc0, 0,0,0);\
      acc1 = __builtin_amdgcn_mfma_f32_16x16x32_bf16(aa0, b2_, acc1, 0,0,0);\
      acc1 = __builtin_amdgcn_mfma_f32_16x16x32_bf16(aa1, b3_, acc1, 0,0,0); }

    LOADB(0, bA0, bA1, bA2, bA3);
#pragma unroll 2
    for (int c = 0; c < NCH; c += 2) {
        LOADB(c + 1, bB0, bB1, bB2, bB3);
        FRAGS_MFMA(c, bA0, bA1, bA2, bA3);
        { const int cn = (c + 2 < NCH) ? c + 2 : 0; LOADB(cn, bA0, bA1, bA2, bA3); }
        FRAGS_MFMA(c + 1, bB0, bB1, bB2, bB3);
    }

    // ---- epilogue: cross-half pre-activation sum, relu+W2, fold, compact ----
    if (half == 0) {
#pragma unroll
        for (int r = 0; r < 4; ++r) {
            hsum[lg * 4 + r][wc * 32 + lr]      = acc0[r];
            hsum[lg * 4 + r][wc * 32 + lr + 16] = acc1[r];
        }
    }
    __syncthreads();
    if (half == 1) {
#pragma unroll
        for (int r = 0; r < 4; ++r) {
            hsum[lg * 4 + r][wc * 32 + lr]      += acc0[r];
            hsum[lg * 4 + r][wc * 32 + lr + 16] += acc1[r];
        }
    }
    __syncthreads();
    if (half == 0) {
        const int c0 = wc * 32 + lr;
        const int c1 = c0 + 16;
        const float bb0 = (c0 < HH) ? b1[c0] : 0.f;
        const float ww0 = (c0 < HH) ? W2[c0] : 0.f;
        const float bb1 = (c1 < HH) ? b1[c1] : 0.f;
        const float ww1 = (c1 < HH) ? W2[c1] : 0.f;
#pragma unroll
        for (int r = 0; r < 4; ++r) {
            const int row = lg * 4 + r;
            float v = fmaf(fmaxf(hsum[row][c0] + bb0, 0.f), ww0,
                           fmaxf(hsum[row][c1] + bb1, 0.f) * ww1);
            v += __shfl_xor(v, 1);
            v += __shfl_xor(v, 2);
            v += __shfl_xor(v, 4);
            v += __shfl_xor(v, 8);
            if (lr == 0) fold[wc][row] = v;
        }
    }
    __syncthreads();
    if (t < 16) {
        const float sv = fold[0][t] + fold[1][t] + fold[2][t] + fold[3][t] + b2[0];
        const int i = r0 + t;
        const int g = bidx[i];
        if (y[i]) {
            int idx = atomicAdd(&cnt1[g], 1);
            if (idx < LCAP) sp[g * LCAP + idx] = sv;
        } else {
            int idx = atomicAdd(&cnt0[g], 1);
            if (idx < LCAP) sn[g * LCAP + idx] = sv;
        }
    }
#undef LOADB
#undef FRAGS_MFMA
}

// grid = NB*8 blocks; block (g, sl) handles pos indices p ≡ sl (mod 8).
__global__ __launch_bounds__(256) void pairsum_kernel(
    const float* __restrict__ sp, const float* __restrict__ sn,
    const int* __restrict__ cnt1, const int* __restrict__ cnt0,
    float* __restrict__ partial)
{
    __shared__ float lsn[LCAP];
    __shared__ float lsp[64];
    __shared__ float wsum[4];
    const int g  = blockIdx.x >> 3;
    const int sl = blockIdx.x & 7;
    const int t  = threadIdx.x;
    const int n1 = min(cnt1[g], LCAP);
    const int n0 = min(cnt0[g], LCAP);
    for (int j = t; j < n0; j += 256) lsn[j] = sn[g * LCAP + j];
    const int np = (n1 > sl) ? ((n1 - sl + 7) >> 3) : 0;
    for (int j = t; j < np; j += 256) lsp[j] = sp[g * LCAP + sl + j * 8];
    __syncthreads();
    float acc = 0.f;
    const int total = np * n0;
    for (int u = t; u < total; u += 256) {
        const int ip = u / n0;
        const int j  = u - ip * n0;
        const float d  = lsn[j] - lsp[ip];          // s_neg - s_pos
        const float ad = fabsf(d);
        const float z  = __builtin_exp2f(-ad * 1.44269504f);
        acc += fmaxf(d, 0.f) + __builtin_log2f(1.f + z) * 0.69314718f;
    }
#pragma unroll
    for (int off = 32; off > 0; off >>= 1) acc += __shfl_xor(acc, off, 64);
    const int wid = t >> 6, lane = t & 63;
    if (lane == 0) wsum[wid] = acc;
    __syncthreads();
    if (t == 0) partial[blockIdx.x] = wsum[0] + wsum[1] + wsum[2] + wsum[3];
}

__global__ __launch_bounds__(256) void finalize_kernel(
    const float* __restrict__ partial,
    const int* __restrict__ cnt1, const int* __restrict__ cnt0,
    float* __restrict__ out)
{
    __shared__ float ws_[4], wc_[4];
    const int t = threadIdx.x;
    float sv = partial[t];   // 256 entries
    float cv = 0.f;
    if (t < NB) cv = (float)min(cnt1[t], LCAP) * (float)min(cnt0[t], LCAP);
#pragma unroll
    for (int off = 32; off > 0; off >>= 1) {
        sv += __shfl_xor(sv, off, 64);
        cv += __shfl_xor(cv, off, 64);
    }
    const int wid = t >> 6, lane = t & 63;
    if (lane == 0) { ws_[wid] = sv; wc_[wid] = cv; }
    __syncthreads();
    if (t == 0)
        out[0] = (ws_[0] + ws_[1] + ws_[2] + ws_[3]) /
                 (wc_[0] + wc_[1] + wc_[2] + wc_[3]);
}

extern "C" void kernel_launch(void* const* d_in, const int* in_sizes, int n_in,
                              void* d_out, int out_size, void* d_ws, size_t ws_size,
                              hipStream_t stream)
{
    const int*   b  = (const int*)d_in[0];
    const float* q  = (const float*)d_in[1];
    const float* x  = (const float*)d_in[2];
    const int*   y  = (const int*)d_in[3];
    const float* W1 = (const float*)d_in[4];
    const float* b1 = (const float*)d_in[5];
    const float* W2 = (const float*)d_in[6];
    const float* b2 = (const float*)d_in[7];
    float* out = (float*)d_out;

    char* base = (char*)d_ws;
    short* w1p     = (short*)base;                          // 512 KB packed B
    float* sp      = (float*)(base + 524288);               // 64 KB
    float* sn      = (float*)(base + 524288 + 65536);       // 64 KB
    int*   cnt1    = (int*)(base + 524288 + 131072);        // 128 B
    int*   cnt0    = cnt1 + NB;                             // 128 B
    float* partial = (float*)(base + 524288 + 131072 + 256);// 1 KB

    prep_w1p<<<KT / 32, 256, 0, stream>>>(W1, w1p, cnt1, cnt0);
    encoder_mfma<<<NN / 16, 512, 0, stream>>>(q, x, w1p, b1, W2, b2,
                                              b, y, sp, sn, cnt1, cnt0);
    pairsum_kernel<<<NB * 8, 256, 0, stream>>>(sp, sn, cnt1, cnt0, partial);
    finalize_kernel<<<1, 256, 0, stream>>>(partial, cnt1, cnt0, out);
}